// Round 3
// baseline (98.883 us; speedup 1.0000x reference)
//
#include <hip/hip_runtime.h>
#include <hip/hip_fp16.h>
#include <math.h>

#define N      512
#define DIMC   128
#define HEADS  4
#define DH     32
#define INDC   5
#define SCALE  0.1767766952966369f   // 32^-0.5

// Virtual output rows of the fused pre-GEMM: all are (row_weights) @ x
//   rows [0,384)   : qkv   (q rows 0..127, k 128..255, v 256..383)
//   rows [384,404) : Aq[(h*5+c)]  composite weight  Wq_rows . W_ind_k
//   rows [404,424) : Ak[(h*5+c)]  composite weight  Wk_rows . W_ind_q
// rows are stored FP16 (halves attn's L2-side K/V traffic; error << threshold)
#define QKV_ROWS 384
#define AQ_BASE  384
#define AK_BASE  404
#define TOT_ROWS 424
#define NROW_BLK (TOT_ROWS / 4)   // 106

// ws layout: [rows fp16: TOT_ROWS*N halves][MhS 64 f32][w_outT 16384 f32]
#define MHS_F    (TOT_ROWS * N / 2)      // float offset after fp16 rows
#define WOUTT_F  (MHS_F + 64)

// ---------------- Kernel 1: fused pre-GEMM + MhS + w_out transpose ----------------
__global__ __launch_bounds__(256) void pre_kernel(const float* __restrict__ w_qkv,
                                                  const float* __restrict__ w_ind,
                                                  const float* __restrict__ x,
                                                  const float* __restrict__ w_out,
                                                  float* __restrict__ ws) {
    const int bx = blockIdx.x;
    const int t  = threadIdx.x;
    __half* rows  = (__half*)ws;
    float* MhS    = ws + MHS_F;
    float* w_outT = ws + WOUTT_F;

    if (bx == NROW_BLK) {
        if (blockIdx.y != 0) return;
        // --- M[h,c,cc] = sum_d w_ind_q[h,d,c] * w_ind_k[h,d,cc], then symmetrize ---
        __shared__ float mraw[HEADS * INDC * INDC];
        if (t < HEADS * INDC * INDC) {
            const int h = t / 25, c = (t / 5) % 5, cc = t % 5;
            float acc = 0.f;
            for (int d = 0; d < DH; ++d)
                acc = fmaf(w_ind[(h * DH + d) * INDC + c],
                           w_ind[(DIMC + h * DH + d) * INDC + cc], acc);
            mraw[t] = acc;
        }
        __syncthreads();
        if (t < 64) {
            const int h = t >> 4, idx = t & 15;
            const int PC[10]  = {0, 0, 0, 0, 1, 1, 1, 2, 2, 3};
            const int PCC[10] = {1, 2, 3, 4, 2, 3, 4, 3, 4, 4};
            float s = 0.f;
            if (idx < 5) {
                s = mraw[h * 25 + idx * 5 + idx];
            } else if (idx < 15) {
                const int c = PC[idx - 5], cc = PCC[idx - 5];
                s = mraw[h * 25 + c * 5 + cc] + mraw[h * 25 + cc * 5 + c];
            }
            MhS[h * 16 + idx] = s;
        }
        // --- transpose w_out (128x128) so the fused outproj reads coalesced ---
        for (int idx = t; idx < DIMC * DIMC; idx += 256) {
            const int o = idx >> 7, c = idx & 127;
            w_outT[c * DIMC + o] = w_out[idx];
        }
        return;
    }

    // --- 4 virtual rows per block, c-major float4 layout in LDS ---
    __shared__ float ws2[4 * DIMC];   // ws2[c*4 + r]
    const int o0 = bx * 4;
    for (int idx = t; idx < 4 * DIMC; idx += 256) {
        const int r = idx & 3, m = idx >> 2;
        const int row = o0 + r;
        float val;
        if (row < QKV_ROWS) {
            val = w_qkv[row * DIMC + m];
        } else if (row < AK_BASE) {              // Aq composite: q-rows . W_ind_k
            const int rr = row - AQ_BASE, h = rr / INDC, c = rr % INDC;
            float acc = 0.f;
            for (int d = 0; d < DH; ++d)
                acc = fmaf(w_qkv[(h * DH + d) * DIMC + m],
                           w_ind[(DIMC + h * DH + d) * INDC + c], acc);
            val = acc;
        } else {                                  // Ak composite: k-rows . W_ind_q
            const int rr = row - AK_BASE, h = rr / INDC, c = rr % INDC;
            float acc = 0.f;
            for (int d = 0; d < DH; ++d)
                acc = fmaf(w_qkv[(DIMC + h * DH + d) * DIMC + m],
                           w_ind[(h * DH + d) * INDC + c], acc);
            val = acc;
        }
        ws2[m * 4 + r] = val;
    }
    __syncthreads();

    const int i = blockIdx.y * 256 + t;   // i-split halves per-block x traffic
    float acc[4] = {0.f, 0.f, 0.f, 0.f};
#pragma unroll 8
    for (int c = 0; c < DIMC; ++c) {
        const float xv = x[c * N + i];
        const float4 wv = *(const float4*)(ws2 + c * 4);
        acc[0] = fmaf(wv.x, xv, acc[0]);
        acc[1] = fmaf(wv.y, xv, acc[1]);
        acc[2] = fmaf(wv.z, xv, acc[2]);
        acc[3] = fmaf(wv.w, xv, acc[3]);
    }
#pragma unroll
    for (int r = 0; r < 4; ++r) rows[(o0 + r) * N + i] = __float2half(acc[r]);
}

// -- Kernel 2: per-i-pair mega kernel, 8 waves: wave w = (head w&3, i-col w>>2) --
// Each wave runs sim -> shuffle-only softmax -> PV for ONE (head,i); grid stays
// 256 (1 block/CU) but 8 waves/block = 2 waves/SIMD for latency hiding.
__global__ __launch_bounds__(512) void attn_kernel(const float* __restrict__ ws,
                                                   const float* __restrict__ ind,
                                                   const float* __restrict__ b_out,
                                                   float* __restrict__ out) {
    const int i0   = blockIdx.x * 2;
    const int t    = threadIdx.x;
    const int lane = t & 63;
    const int w    = t >> 6;      // 0..7
    const int h    = w & 3;       // head
    const int ii   = w >> 2;      // which i column
    const int i    = i0 + ii;

    const __half* rows  = (const __half*)ws;
    const float* MhS    = ws + MHS_F;
    const float* w_outT = ws + WOUTT_F;

    __shared__ float qs[2][DIMC];
    __shared__ float aqs[2][HEADS * INDC];
    __shared__ float msS[HEADS * 16];
    __shared__ float red[8][DH][32];        // 32 KB: per-wave 32x32 transpose buf
    __shared__ float attv[2][DIMC];
    __shared__ float outred[8][2][DIMC];    // 8 KB

    // ---- issue indicator loads (cold HBM) FIRST, before the staging barrier ----
    // lane g = lane + 64*s owns j-group [4g, 4g+3] of this wave's i row.
    float4 ic[2][INDC];
#pragma unroll
    for (int s = 0; s < 2; ++s) {
        const int g = lane + 64 * s;
#pragma unroll
        for (int c = 0; c < INDC; ++c)
            ic[s][c] = ((const float4*)(ind + (c * N + i) * N))[g];
    }

    // ---- stage q / aq / MhS into LDS ----
    const __half* q  = rows;
    const __half* Aq = rows + 3 * DIMC * N;
    if (t < DIMC) {
        qs[0][t] = __half2float(q[t * N + i0]);
    } else if (t < 2 * DIMC) {
        qs[1][t - DIMC] = __half2float(q[(t - DIMC) * N + i0 + 1]);
    } else if (t < 2 * DIMC + 2 * HEADS * INDC) {
        const int r2 = t - 2 * DIMC;
        const int iw = r2 / (HEADS * INDC), r = r2 % (HEADS * INDC);
        aqs[iw][r] = __half2float(Aq[r * N + i0 + iw]);
    } else if (t < 2 * DIMC + 2 * HEADS * INDC + 64) {
        const int r = t - 2 * DIMC - 2 * HEADS * INDC;
        msS[r] = MhS[r];
    }
    __syncthreads();

    const float2* k4  = (const float2*)(rows + DIMC * N);           // half4 rows
    const float2* v4  = (const float2*)(rows + 2 * DIMC * N);
    const float2* Ak4 = (const float2*)(rows + (3 * DIMC + HEADS * INDC) * N);

    // ---- sim: this wave's (head,i), 4 j per lane per s ----
    float4 sr[2];
    float m = -1e30f;
#pragma unroll
    for (int s = 0; s < 2; ++s) {
        const int g = lane + 64 * s;
        float4 a = {0.f, 0.f, 0.f, 0.f};
#pragma unroll
        for (int d = 0; d < DH; ++d) {
            const float2 raw = k4[(h * DH + d) * 128 + g];
            const float2 fa = __half22float2(*(const __half2*)&raw.x);
            const float2 fb = __half22float2(*(const __half2*)&raw.y);
            const float qv = qs[ii][h * DH + d];
            a.x = fmaf(qv, fa.x, a.x); a.y = fmaf(qv, fa.y, a.y);
            a.z = fmaf(qv, fb.x, a.z); a.w = fmaf(qv, fb.y, a.w);
        }
#pragma unroll
        for (int c = 0; c < INDC; ++c) {
            const float2 raw = Ak4[(h * INDC + c) * 128 + g];
            const float2 fa = __half22float2(*(const __half2*)&raw.x);
            const float2 fb = __half22float2(*(const __half2*)&raw.y);
            const float b0 = aqs[ii][h * INDC + c];
            const float4 v0 = ic[s][c];
            a.x = fmaf(b0 + fa.x, v0.x, a.x); a.y = fmaf(b0 + fa.y, v0.y, a.y);
            a.z = fmaf(b0 + fb.x, v0.z, a.z); a.w = fmaf(b0 + fb.y, v0.w, a.w);
        }
        // quadratic term: 15 symmetric (c,cc) pairs, coefficients MhS
        const int PCf[15]  = {0, 1, 2, 3, 4, 0, 0, 0, 0, 1, 1, 1, 2, 2, 3};
        const int PCCf[15] = {0, 1, 2, 3, 4, 1, 2, 3, 4, 2, 3, 4, 3, 4, 4};
#pragma unroll
        for (int p = 0; p < 15; ++p) {
            const float sv = msS[h * 16 + p];
            const float4 A = ic[s][PCf[p]], B = ic[s][PCCf[p]];
            a.x = fmaf(sv, A.x * B.x, a.x); a.y = fmaf(sv, A.y * B.y, a.y);
            a.z = fmaf(sv, A.z * B.z, a.z); a.w = fmaf(sv, A.w * B.w, a.w);
        }
        sr[s] = make_float4(SCALE * a.x, SCALE * a.y, SCALE * a.z, SCALE * a.w);
        m = fmaxf(m, fmaxf(fmaxf(sr[s].x, sr[s].y), fmaxf(sr[s].z, sr[s].w)));
    }

    // ---- softmax: pure in-wave butterflies, no barriers ----
#pragma unroll
    for (int off = 1; off < 64; off <<= 1)
        m = fmaxf(m, __shfl_xor(m, off, 64));
    float4 e[2];
    float sum = 0.f;
#pragma unroll
    for (int s = 0; s < 2; ++s) {
        e[s].x = __expf(sr[s].x - m); e[s].y = __expf(sr[s].y - m);
        e[s].z = __expf(sr[s].z - m); e[s].w = __expf(sr[s].w - m);
        sum += (e[s].x + e[s].y) + (e[s].z + e[s].w);
    }
#pragma unroll
    for (int off = 1; off < 64; off <<= 1)
        sum += __shfl_xor(sum, off, 64);
    const float rnorm = 1.f / sum;   // folded into attv store

    // ---- PV: unnormalized P (registers) x V, wave-local ----
    float acc[DH];
#pragma unroll
    for (int d = 0; d < DH; ++d) acc[d] = 0.f;
#pragma unroll
    for (int s = 0; s < 2; ++s) {
        const int g = lane + 64 * s;
        const float4 p = e[s];
#pragma unroll
        for (int d = 0; d < DH; ++d) {
            const float2 raw = v4[(h * DH + d) * 128 + g];
            const float2 fa = __half22float2(*(const __half2*)&raw.x);
            const float2 fb = __half22float2(*(const __half2*)&raw.y);
            acc[d] = fmaf(p.x, fa.x, fmaf(p.y, fa.y,
                     fmaf(p.z, fb.x, fmaf(p.w, fb.y, acc[d]))));
        }
    }

    // ---- cross-lane reduce: shfl fold 64->32, then 32x32 XOR transpose ----
    {
#pragma unroll
        for (int d = 0; d < DH; ++d)
            acc[d] += __shfl_xor(acc[d], 32, 64);
        const int l5 = lane & 31;
        if (lane < 32) {
#pragma unroll
            for (int dd = 0; dd < DH; ++dd) red[w][dd][l5 ^ dd] = acc[dd];
        }
        // no barrier needed: same wave writes then reads its own buffer
        if (lane < 32) {
            float s = 0.f;
#pragma unroll
            for (int kk = 0; kk < 32; ++kk) s += red[w][l5][kk ^ l5];
            attv[ii][h * DH + l5] = s * rnorm;
        }
    }
    __syncthreads();

    // ---- fused output projection: out[:, i0+iw] = w_out @ attv[iw] + b ----
    {
        const int po  = t & 63;         // float2 o-pair index
        const int grp = t >> 6;         // 8 groups of 16 c each
        const float2* wT2 = (const float2*)w_outT;
        float2 a0 = {0.f, 0.f}, a1 = {0.f, 0.f};
#pragma unroll
        for (int c = grp * 16; c < grp * 16 + 16; ++c) {
            const float2 wv = wT2[c * 64 + po];                // shared load
            const float av0 = attv[0][c], av1 = attv[1][c];
            a0.x = fmaf(wv.x, av0, a0.x); a0.y = fmaf(wv.y, av0, a0.y);
            a1.x = fmaf(wv.x, av1, a1.x); a1.y = fmaf(wv.y, av1, a1.y);
        }
        ((float2*)&outred[grp][0][0])[po] = a0;
        ((float2*)&outred[grp][1][0])[po] = a1;
    }
    __syncthreads();
    if (t < 256) {
        const int o = t & 127, iw = t >> 7;
        float s = 0.f;
#pragma unroll
        for (int g = 0; g < 8; ++g) s += outred[g][iw][o];
        out[o * N + i0 + iw] = s + b_out[o];
    }
}

extern "C" void kernel_launch(void* const* d_in, const int* in_sizes, int n_in,
                              void* d_out, int out_size, void* d_ws, size_t ws_size,
                              hipStream_t stream) {
    const float* x         = (const float*)d_in[0];  // (1,128,512)
    const float* indicator = (const float*)d_in[1];  // (1,5,512,512)
    const float* w_qkv     = (const float*)d_in[2];  // (384,128)
    const float* w_ind     = (const float*)d_in[3];  // (256,5)
    const float* w_out     = (const float*)d_in[4];  // (128,128)
    const float* b_out     = (const float*)d_in[5];  // (128,)
    float* out = (float*)d_out;                      // (1,128,512)
    float* ws  = (float*)d_ws;

    pre_kernel<<<dim3(NROW_BLK + 1, 2), 256, 0, stream>>>(w_qkv, w_ind, x, w_out, ws);
    attn_kernel<<<N / 2, 512, 0, stream>>>(ws, indicator, b_out, out);
}